// Round 4
// baseline (230.569 us; speedup 1.0000x reference)
//
#include <hip/hip_runtime.h>

// DWT db4 depthwise stride-2 decomposition.
// x: [B=32, T=16384, C=64] f32 -> out: [B, T2=8190, 2C=128] f32
// out[b,t,c]    = sum_k lo[k] * x[b, reflect(2t+k-1), c]      (c < 64)
// out[b,t,64+c] = sum_k hi[k] * x[b, reflect(2t+k-1), c]
// reflect: m<0 -> -m ; m>T-1 -> 2(T-1)-m
//
// R4 = R3 with the nt-store type fixed: one thread = (4 channels via float4)
// x (quad of outputs t..t+3). Quad needs rows 2t-1 .. 2t+13 (15 rows); all 15
// float4 loads are independent and issued up front => 15 outstanding
// loads/thread. Logical over-read 1.875x absorbed by L1/L2.
// Stores non-temporal via ext_vector_type (HIP float4 class is rejected by
// __builtin_nontemporal_store).

#define BT   32
#define TT   16384
#define CC   64
#define T2   8190       // T/2 - 2
#define OC   128        // 2*CC
#define QPT  4          // outputs per thread
#define NQ   ((T2 + QPT - 1) / QPT)   // 2048 quads

typedef float vf4 __attribute__((ext_vector_type(4)));

__global__ __launch_bounds__(256) void dwt_db4_quad_kernel(
    const float* __restrict__ x,
    const float* __restrict__ dec_lo,
    const float* __restrict__ dec_hi,
    float* __restrict__ out)
{
    const int tid  = threadIdx.x;
    const int cg   = tid & 15;               // channel group: 4 ch via vf4
    const int qs   = tid >> 4;               // 0..15: quad slot within block
    const int quad = blockIdx.x * 16 + qs;
    const int b    = blockIdx.y;
    if (quad >= NQ) return;

    const int t0 = quad * QPT;
    const int c4 = cg * 4;

    // Filters: uniform addresses -> scalar broadcast loads.
    float flo[8], fhi[8];
    #pragma unroll
    for (int k = 0; k < 8; ++k) { flo[k] = dec_lo[k]; fhi[k] = dec_hi[k]; }

    const float* __restrict__ xb = x + (size_t)b * TT * CC;

    // 15-row window covering outputs t0..t0+3; all loads independent.
    const int m0 = 2 * t0 - 1;
    vf4 w[15];
    #pragma unroll
    for (int i = 0; i < 15; ++i) {
        int m  = m0 + i;
        int mm = m < 0 ? -m : m;                          // left reflect (t0==0)
        mm     = mm > (TT - 1) ? 2 * (TT - 1) - mm : mm;  // right reflect (tail)
        w[i] = *reinterpret_cast<const vf4*>(xb + (size_t)mm * CC + c4);
    }

    vf4 alo[QPT], ahi[QPT];
    #pragma unroll
    for (int j = 0; j < QPT; ++j) {
        alo[j] = (vf4)0.0f;
        ahi[j] = (vf4)0.0f;
    }

    #pragma unroll
    for (int j = 0; j < QPT; ++j) {
        #pragma unroll
        for (int k = 0; k < 8; ++k) {
            const vf4 v = w[2 * j + k];
            alo[j] += flo[k] * v;
            ahi[j] += fhi[k] * v;
        }
    }

    float* __restrict__ ob = out + (size_t)b * T2 * OC + (size_t)t0 * OC;
    #pragma unroll
    for (int j = 0; j < QPT; ++j) {
        if (t0 + j < T2) {
            __builtin_nontemporal_store(alo[j],
                reinterpret_cast<vf4*>(ob + (size_t)j * OC + c4));
            __builtin_nontemporal_store(ahi[j],
                reinterpret_cast<vf4*>(ob + (size_t)j * OC + CC + c4));
        }
    }
}

extern "C" void kernel_launch(void* const* d_in, const int* in_sizes, int n_in,
                              void* d_out, int out_size, void* d_ws, size_t ws_size,
                              hipStream_t stream)
{
    const float* x      = (const float*)d_in[0];
    const float* dec_lo = (const float*)d_in[1];
    const float* dec_hi = (const float*)d_in[2];
    float*       out    = (float*)d_out;

    dim3 block(256);
    // 16 quads per block -> 2048/16 = 128 tiles; x 32 batches = 4096 blocks
    dim3 grid((NQ + 15) / 16, BT);

    hipLaunchKernelGGL(dwt_db4_quad_kernel, grid, block, 0, stream,
                       x, dec_lo, dec_hi, out);
}